// Round 4
// baseline (580.863 us; speedup 1.0000x reference)
//
#include <hip/hip_runtime.h>

// ConvLatticeModule: out[N,32] = gather(LV, idx)[N,288] @ W[288,32] + bias
// fp32 in/out, bf16 MFMA internally (absmax 0.031 << 0.099 threshold).
//
// R4: single kernel (R3's bf16 staging pre-pass REVERTED — cost ~250us/launch
// and raised L2-miss traffic: bf16 rows = half a 128B line, random gather gets
// no adjacent-row reuse; fp32 row = exactly one line is the optimal granule).
// Kept from R3: W fragments in LDS (18 KB) -> 40 VGPRs. New: grid 2048 =
// 8 blocks/CU, __launch_bounds__(256,8) -> ~100% occupancy to test whether
// R2's 2.97 TB/s at 34% occupancy was gather-latency-bound.
//
// MFMA 16x16x32_bf16, one wave = 16 vertices x 32 filters.
//   A layout: A[m=lane&15][k=quad*8+j]  (quad=lane>>4); lanes m,m+16,m+32,
//   m+48 read the four 32B chunks of one 128B row -> full-line coalescing.
//   C/D layout: col(filter)=lane&15, row(vertex)=quad*4+reg   [m89]

typedef __attribute__((ext_vector_type(8))) short short8;
typedef __attribute__((ext_vector_type(4))) float floatx4;

__device__ __forceinline__ unsigned short f2bf(float f) {
    union { float f; unsigned int i; } x;
    x.f = f;
    unsigned int i = x.i;
    i += 0x7fffu + ((i >> 16) & 1u);   // RNE
    return (unsigned short)(i >> 16);
}

#define KNB 9

__global__ __launch_bounds__(256, 8) void conv_lattice_kernel(
    const float* __restrict__ lv,     // [N][32] fp32
    const int* __restrict__ nbr,      // [N][9]  int32
    const float* __restrict__ w,      // [288][32] fp32
    const float* __restrict__ bias,   // [32] fp32
    float* __restrict__ out,          // [N][32] fp32
    int ntiles)
{
    const int lane = (int)(threadIdx.x & 63u);
    const int m = lane & 15;
    const int quad = lane >> 4;
    const int tid = (int)threadIdx.x;

    // W fragments in LDS, layout [k][t][quad][m][j], j contiguous (16B units):
    // flat i = (((k*2+t)*4+quad)*16 + m)*8 + j
    __shared__ unsigned short wlds[KNB * 2 * 4 * 16 * 8];  // 9216 elems, 18 KB
    for (int i = tid; i < KNB * 2 * 4 * 16 * 8; i += 256) {
        const int j  = i & 7;
        const int mm = (i >> 3) & 15;
        const int qq = (i >> 7) & 3;
        const int tt = (i >> 9) & 1;
        const int kk = i >> 10;
        wlds[i] = f2bf(w[(kk * 32 + qq * 8 + j) * 32 + tt * 16 + mm]);
    }
    __syncthreads();

    const float bias0 = bias[m];
    const float bias1 = bias[m + 16];

    // per-lane elem offset of its B fragment within a (k,t) slab of 512
    const int bofs = (quad * 16 + m) * 8;

    const int wave = (int)((blockIdx.x * blockDim.x + threadIdx.x) >> 6);
    const int nw = (int)((gridDim.x * blockDim.x) >> 6);

    for (int t = wave; t < ntiles; t += nw) {
        const int vbase = t << 4;
        const int ibase = (vbase + m) * KNB;

        // issue all index loads, then all gathers, before any MFMA waits
        int idx[KNB];
#pragma unroll
        for (int k = 0; k < KNB; ++k) idx[k] = nbr[ibase + k];

        floatx4 lo[KNB], hi[KNB];
#pragma unroll
        for (int k = 0; k < KNB; ++k) {
            const floatx4* rp = (const floatx4*)(lv + (size_t)idx[k] * 32 + quad * 8);
            lo[k] = rp[0];
            hi[k] = rp[1];
        }

        floatx4 acc0 = {0.f, 0.f, 0.f, 0.f};
        floatx4 acc1 = {0.f, 0.f, 0.f, 0.f};
#pragma unroll
        for (int k = 0; k < KNB; ++k) {
            short8 a;
#pragma unroll
            for (int j = 0; j < 4; ++j) {
                a[j]     = (short)f2bf(lo[k][j]);
                a[j + 4] = (short)f2bf(hi[k][j]);
            }
            const short8 b0 = *(const short8*)&wlds[(k * 2 + 0) * 512 + bofs];
            const short8 b1 = *(const short8*)&wlds[(k * 2 + 1) * 512 + bofs];
            acc0 = __builtin_amdgcn_mfma_f32_16x16x32_bf16(a, b0, acc0, 0, 0, 0);
            acc1 = __builtin_amdgcn_mfma_f32_16x16x32_bf16(a, b1, acc1, 0, 0, 0);
        }

        const int vrow = vbase + quad * 4;
#pragma unroll
        for (int i = 0; i < 4; ++i) {
            float* o = out + (size_t)(vrow + i) * 32;
            o[m]      = acc0[i] + bias0;
            o[m + 16] = acc1[i] + bias1;
        }
    }
}

extern "C" void kernel_launch(void* const* d_in, const int* in_sizes, int n_in,
                              void* d_out, int out_size, void* d_ws, size_t ws_size,
                              hipStream_t stream) {
    const float* lv   = (const float*)d_in[0];
    const int*   nbr  = (const int*)d_in[1];
    const float* w    = (const float*)d_in[2];
    const float* bias = (const float*)d_in[3];
    float*       out  = (float*)d_out;

    const int n = in_sizes[0] / 32;
    const int ntiles = n / 16;

    // 2048 blocks = 8 blocks/CU resident (LDS 18KB x 8 = 144KB <= 160KB,
    // 40 VGPR <= 64-reg cap at 8 waves/EU). Grid-stride ~7.6 tiles/wave
    // amortizes the LDS W-staging.
    hipLaunchKernelGGL(conv_lattice_kernel, dim3(2048), dim3(256), 0, stream,
                       lv, nbr, w, bias, out, ntiles);
}